// Round 2
// baseline (381.759 us; speedup 1.0000x reference)
//
#include <hip/hip_runtime.h>
#include <hip/hip_bf16.h>

// Problem: B=2, T=2048, C=1024, H=16, HD=64, R=32, LORA_SCALE=0.5
// Inputs/outputs are FLOAT32 (round-1 NaN proved bf16 reinterpretation wrong).
// Strategy: convert params+x to bf16 in ws, run bf16-MFMA pipeline, f32 out.
//   t1 = 0.5 * x @ la_attn^T                      (lora_t)
//   qkv = x @ w_attn^T + b_attn + t1 @ lb_attn^T  (gemm_lora, LoRA as extra K-tile)
//   y = causal_flash_attention(qkv)               (flash_attn, MFMA)
//   t2 = 0.5 * y @ la_proj^T                      (lora_t)
//   out = y @ w_proj^T + b_proj + t2 @ lb_proj^T  (gemm_lora, f32 store)

typedef __attribute__((ext_vector_type(8))) short short8;   // 8 x bf16 (4 VGPRs)
typedef __attribute__((ext_vector_type(4))) float float4v;  // MFMA accumulator

static __device__ __forceinline__ float b2f(ushort u) {
  union { uint i; float f; } v; v.i = ((uint)u) << 16; return v.f;
}
static __device__ __forceinline__ ushort f2b(float f) {
  union { float f; uint i; } v; v.f = f;
  uint i = v.i + 0x7fffu + ((v.i >> 16) & 1u);  // RNE
  return (ushort)(i >> 16);
}
static __device__ __forceinline__ float4v zero4() {
  float4v z = {0.f, 0.f, 0.f, 0.f}; return z;
}

// ---------------- f32 -> bf16 conversion (grid-stride over float4 chunks)
__global__ __launch_bounds__(256) void f32_to_bf16(
    const float* __restrict__ in, ushort* __restrict__ out, int n4) {
  int stride = gridDim.x * blockDim.x;
  for (int i = blockIdx.x * blockDim.x + threadIdx.x; i < n4; i += stride) {
    float4 v = ((const float4*)in)[i];
    union { ushort u[4]; uint2 p; } o;
    o.u[0] = f2b(v.x); o.u[1] = f2b(v.y); o.u[2] = f2b(v.z); o.u[3] = f2b(v.w);
    ((uint2*)out)[i] = o.p;
  }
}

// ---------------- LoRA down-projection: T[m][r] = 0.5 * sum_k X[m][k]*La[r][k]
// X: [4096,1024] bf16, La: [32,1024] bf16, T: [4096,32] bf16
__global__ __launch_bounds__(256) void lora_t(
    const ushort* __restrict__ X, const ushort* __restrict__ La,
    ushort* __restrict__ T) {
  const int tid = threadIdx.x;
  const int m = blockIdx.x * 8 + (tid >> 5);
  const int r = tid & 31;
  const uint2* xr = (const uint2*)(X + (size_t)m * 1024);
  const uint2* lr = (const uint2*)(La + (size_t)r * 1024);
  float s = 0.f;
  for (int kk = 0; kk < 256; ++kk) {
    uint2 xv = xr[kk], lv = lr[kk];
    s += b2f((ushort)(xv.x)) * b2f((ushort)(lv.x));
    s += b2f((ushort)(xv.x >> 16)) * b2f((ushort)(lv.x >> 16));
    s += b2f((ushort)(xv.y)) * b2f((ushort)(lv.y));
    s += b2f((ushort)(xv.y >> 16)) * b2f((ushort)(lv.y >> 16));
  }
  T[(size_t)m * 32 + r] = f2b(0.5f * s);
}

// ---------------- GEMM + LoRA: out[m][n] = sum_k A[m][k]W[n][k] + bias[n]
//                                          + sum_r T1[m][r]Lb[n][r]
// 128x128 block tile, 4 waves (2x2 of 64x64), 16x16x32 bf16 MFMA, BK=32.
// LoRA handled as one extra K-tile (kt == K/32) reading T1/Lb (row stride 32).
#define GPAD 56  // 32 + 24 elements: 112B rows, 16B-aligned
template <bool OUTF32>
__global__ __launch_bounds__(256, 2) void gemm_lora(
    const ushort* __restrict__ A, const ushort* __restrict__ W,
    const float* __restrict__ bias,
    const ushort* __restrict__ T1, const ushort* __restrict__ Lb,
    void* __restrict__ outv, int M, int N, int K) {
  __shared__ __attribute__((aligned(16))) ushort As[128 * GPAD];
  __shared__ __attribute__((aligned(16))) ushort Ws[128 * GPAD];
  const int tid = threadIdx.x;
  const int lane = tid & 63;
  const int wv = tid >> 6;
  const int l15 = lane & 15;
  const int quad = lane >> 4;
  const int m0 = blockIdx.y * 128;
  const int n0 = blockIdx.x * 128;
  const int wm = (wv >> 1) * 64;
  const int wn = (wv & 1) * 64;

  float4v acc[4][4];
#pragma unroll
  for (int i = 0; i < 4; i++)
#pragma unroll
    for (int j = 0; j < 4; j++) acc[i][j] = zero4();

  const int KT = K >> 5;
  for (int kt = 0; kt <= KT; ++kt) {
    const ushort* srcA; const ushort* srcW; int lda, ldw, kofs;
    if (kt < KT) { srcA = A; lda = K; srcW = W; ldw = K; kofs = kt * 32; }
    else         { srcA = T1; lda = 32; srcW = Lb; ldw = 32; kofs = 0; }
    if (kt) __syncthreads();
#pragma unroll
    for (int c = 0; c < 2; ++c) {
      int chunk = tid * 2 + c;           // 512 chunks: 128 rows x 4 subs
      int row = chunk >> 2, sub = chunk & 3;
      uint4 va = *(const uint4*)(srcA + (size_t)(m0 + row) * lda + kofs + sub * 8);
      uint4 vw = *(const uint4*)(srcW + (size_t)(n0 + row) * ldw + kofs + sub * 8);
      *(uint4*)(&As[row * GPAD + sub * 8]) = va;
      *(uint4*)(&Ws[row * GPAD + sub * 8]) = vw;
    }
    __syncthreads();
    short8 af[4], wf[4];
#pragma unroll
    for (int i = 0; i < 4; i++)
      af[i] = *(const short8*)&As[(wm + i * 16 + l15) * GPAD + quad * 8];
#pragma unroll
    for (int j = 0; j < 4; j++)
      wf[j] = *(const short8*)&Ws[(wn + j * 16 + l15) * GPAD + quad * 8];
#pragma unroll
    for (int i = 0; i < 4; i++)
#pragma unroll
      for (int j = 0; j < 4; j++)
        acc[i][j] = __builtin_amdgcn_mfma_f32_16x16x32_bf16(af[i], wf[j], acc[i][j], 0, 0, 0);
  }
  // epilogue: C/D layout row = quad*4 + r, col = l15
#pragma unroll
  for (int i = 0; i < 4; i++) {
    int gm = m0 + wm + i * 16 + quad * 4;
#pragma unroll
    for (int j = 0; j < 4; j++) {
      int gn = n0 + wn + j * 16 + l15;
      float bb = bias[gn];
#pragma unroll
      for (int r = 0; r < 4; r++) {
        float val = acc[i][j][r] + bb;
        if (OUTF32) ((float*)outv)[(size_t)(gm + r) * N + gn] = val;
        else        ((ushort*)outv)[(size_t)(gm + r) * N + gn] = f2b(val);
      }
    }
  }
}

// ---------------- Causal flash attention, bf16 MFMA.
// qkv: [4096, 3072] (q | k | v per 1024 cols, head h at cols h*64).
// Block = (qb, bh): 64 Q rows, 4 waves x 16 rows. K/V tiles of 64 keys.
#define FPAD 72  // 64 + 8: 144B rows
__global__ __launch_bounds__(256, 2) void flash_attn(
    const ushort* __restrict__ qkv, ushort* __restrict__ y) {
  __shared__ __attribute__((aligned(16))) ushort Qs[64 * FPAD];
  __shared__ __attribute__((aligned(16))) ushort Ks[64 * FPAD];
  __shared__ __attribute__((aligned(16))) ushort Vts[64 * FPAD];  // [d][key]
  __shared__ __attribute__((aligned(16))) ushort Ps[4 * 16 * FPAD];
  const int tid = threadIdx.x;
  const int lane = tid & 63;
  const int wv = tid >> 6;
  const int l15 = lane & 15;
  const int quad = lane >> 4;
  const int qb = blockIdx.x;
  const int bh = blockIdx.y;
  const int b = bh >> 4, h = bh & 15;
  const size_t base = (size_t)b * 2048 * 3072 + (size_t)h * 64;
  const ushort* qp = qkv + base;
  const ushort* kp = qkv + base + 1024;
  const ushort* vp = qkv + base + 2048;

  // stage Q tile, pre-scaled by 1/sqrt(64) = 0.125 (exact in bf16)
#pragma unroll
  for (int c = 0; c < 2; ++c) {
    int chunk = tid * 2 + c;             // 512 chunks: 64 rows x 8 subs
    int row = chunk >> 3, sub = chunk & 7;
    union { uint4 v; ushort u[8]; } t;
    t.v = *(const uint4*)(qp + (size_t)(qb * 64 + row) * 3072 + sub * 8);
#pragma unroll
    for (int e = 0; e < 8; e++) t.u[e] = f2b(b2f(t.u[e]) * 0.125f);
    *(uint4*)(&Qs[row * FPAD + sub * 8]) = t.v;
  }

  float4v acc[4];
#pragma unroll
  for (int jt = 0; jt < 4; jt++) acc[jt] = zero4();
  float m_i[4], l_i[4];
#pragma unroll
  for (int r = 0; r < 4; r++) { m_i[r] = -1e30f; l_i[r] = 0.f; }

  __syncthreads();
  short8 aq0 = *(const short8*)&Qs[(wv * 16 + l15) * FPAD + quad * 8];
  short8 aq1 = *(const short8*)&Qs[(wv * 16 + l15) * FPAD + 32 + quad * 8];

  for (int kb = 0; kb <= qb; ++kb) {
    __syncthreads();
#pragma unroll
    for (int c = 0; c < 2; ++c) {
      int chunk = tid * 2 + c;
      int row = chunk >> 3, sub = chunk & 7;
      uint4 kvv = *(const uint4*)(kp + (size_t)(kb * 64 + row) * 3072 + sub * 8);
      *(uint4*)(&Ks[row * FPAD + sub * 8]) = kvv;
      union { uint4 v; ushort u[8]; } t;
      t.v = *(const uint4*)(vp + (size_t)(kb * 64 + row) * 3072 + sub * 8);
#pragma unroll
      for (int e = 0; e < 8; e++) Vts[(sub * 8 + e) * FPAD + row] = t.u[e];
    }
    __syncthreads();

    // S = Qs @ K^T : 4 key sub-tiles of 16, K-dim 64 = 2 MFMA steps
    float4v s[4];
#pragma unroll
    for (int j = 0; j < 4; j++) {
      short8 bk0 = *(const short8*)&Ks[(j * 16 + l15) * FPAD + quad * 8];
      short8 bk1 = *(const short8*)&Ks[(j * 16 + l15) * FPAD + 32 + quad * 8];
      s[j] = zero4();
      s[j] = __builtin_amdgcn_mfma_f32_16x16x32_bf16(aq0, bk0, s[j], 0, 0, 0);
      s[j] = __builtin_amdgcn_mfma_f32_16x16x32_bf16(aq1, bk1, s[j], 0, 0, 0);
    }
    // causal mask (S rows: q = qb*64 + wv*16 + quad*4 + r; cols: key)
    const int qrow0 = qb * 64 + wv * 16 + quad * 4;
#pragma unroll
    for (int j = 0; j < 4; j++) {
      int key = kb * 64 + j * 16 + l15;
#pragma unroll
      for (int r = 0; r < 4; r++)
        if (key > qrow0 + r) s[j][r] = -1e30f;
    }
    // online softmax per row (row spread over 16 lanes of the quad)
    float al[4];
#pragma unroll
    for (int r = 0; r < 4; r++) {
      float m = fmaxf(fmaxf(s[0][r], s[1][r]), fmaxf(s[2][r], s[3][r]));
      m = fmaxf(m, __shfl_xor(m, 1, 64));
      m = fmaxf(m, __shfl_xor(m, 2, 64));
      m = fmaxf(m, __shfl_xor(m, 4, 64));
      m = fmaxf(m, __shfl_xor(m, 8, 64));
      float mn = fmaxf(m_i[r], m);
      al[r] = __expf(m_i[r] - mn);
      m_i[r] = mn;
      float sum = 0.f;
#pragma unroll
      for (int j = 0; j < 4; j++) {
        float p = __expf(s[j][r] - mn);
        s[j][r] = p;
        sum += p;
      }
      sum += __shfl_xor(sum, 1, 64);
      sum += __shfl_xor(sum, 2, 64);
      sum += __shfl_xor(sum, 4, 64);
      sum += __shfl_xor(sum, 8, 64);
      l_i[r] = l_i[r] * al[r] + sum;
    }
#pragma unroll
    for (int jt = 0; jt < 4; jt++)
#pragma unroll
      for (int r = 0; r < 4; r++) acc[jt][r] *= al[r];

    // P: C/D layout -> A layout via per-wave LDS round-trip
    const int pb = wv * 16 * FPAD;
#pragma unroll
    for (int j = 0; j < 4; j++)
#pragma unroll
      for (int r = 0; r < 4; r++)
        Ps[pb + (quad * 4 + r) * FPAD + j * 16 + l15] = f2b(s[j][r]);

    // O += P @ V  (B-operand from transposed Vts so frags are contiguous)
#pragma unroll
    for (int kt2 = 0; kt2 < 2; ++kt2) {
      short8 pa = *(const short8*)&Ps[pb + l15 * FPAD + kt2 * 32 + quad * 8];
#pragma unroll
      for (int jt = 0; jt < 4; jt++) {
        short8 vb = *(const short8*)&Vts[(jt * 16 + l15) * FPAD + kt2 * 32 + quad * 8];
        acc[jt] = __builtin_amdgcn_mfma_f32_16x16x32_bf16(pa, vb, acc[jt], 0, 0, 0);
      }
    }
  }
  // epilogue: y[b*2048 + t][h*64 + d]
#pragma unroll
  for (int jt = 0; jt < 4; jt++)
#pragma unroll
    for (int r = 0; r < 4; r++) {
      int t = qb * 64 + wv * 16 + quad * 4 + r;
      y[(size_t)(b * 2048 + t) * 1024 + h * 64 + jt * 16 + l15] =
          f2b(acc[jt][r] / l_i[r]);
    }
}

extern "C" void kernel_launch(void* const* d_in, const int* in_sizes, int n_in,
                              void* d_out, int out_size, void* d_ws, size_t ws_size,
                              hipStream_t stream) {
  const float* x       = (const float*)d_in[0];
  const float* w_attn  = (const float*)d_in[1];
  const float* b_attn  = (const float*)d_in[2];
  const float* la_attn = (const float*)d_in[3];
  const float* lb_attn = (const float*)d_in[4];
  const float* w_proj  = (const float*)d_in[5];
  const float* b_proj  = (const float*)d_in[6];
  const float* la_proj = (const float*)d_in[7];
  const float* lb_proj = (const float*)d_in[8];

  // bf16 workspace layout (element offsets; all multiples of 8 for 16B align)
  ushort* p = (ushort*)d_ws;
  ushort* xb   = p; p += (size_t)4096 * 1024;   // x
  ushort* wab  = p; p += (size_t)3072 * 1024;   // w_attn
  ushort* lab  = p; p += (size_t)32 * 1024;     // la_attn
  ushort* lbb  = p; p += (size_t)3072 * 32;     // lb_attn
  ushort* wpb  = p; p += (size_t)1024 * 1024;   // w_proj
  ushort* lpb  = p; p += (size_t)32 * 1024;     // la_proj
  ushort* lqb  = p; p += (size_t)1024 * 32;     // lb_proj
  ushort* t1b  = p; p += (size_t)4096 * 32;
  ushort* t2b  = p; p += (size_t)4096 * 32;
  ushort* qkvb = p; p += (size_t)4096 * 3072;
  ushort* yb   = p; p += (size_t)4096 * 1024;

  // f32 -> bf16 conversions
  f32_to_bf16<<<dim3(2048), dim3(256), 0, stream>>>(x, xb, 4194304 / 4);
  f32_to_bf16<<<dim3(2048), dim3(256), 0, stream>>>(w_attn, wab, 3145728 / 4);
  f32_to_bf16<<<dim3(32), dim3(256), 0, stream>>>(la_attn, lab, 32768 / 4);
  f32_to_bf16<<<dim3(96), dim3(256), 0, stream>>>(lb_attn, lbb, 98304 / 4);
  f32_to_bf16<<<dim3(1024), dim3(256), 0, stream>>>(w_proj, wpb, 1048576 / 4);
  f32_to_bf16<<<dim3(32), dim3(256), 0, stream>>>(la_proj, lpb, 32768 / 4);
  f32_to_bf16<<<dim3(32), dim3(256), 0, stream>>>(lb_proj, lqb, 32768 / 4);

  lora_t<<<dim3(512), dim3(256), 0, stream>>>(xb, lab, t1b);
  gemm_lora<false><<<dim3(24, 32), dim3(256), 0, stream>>>(
      xb, wab, b_attn, t1b, lbb, qkvb, 4096, 3072, 1024);
  flash_attn<<<dim3(32, 32), dim3(256), 0, stream>>>(qkvb, yb);
  lora_t<<<dim3(512), dim3(256), 0, stream>>>(yb, lpb, t2b);
  gemm_lora<true><<<dim3(8, 32), dim3(256), 0, stream>>>(
      yb, wpb, b_proj, t2b, lqb, d_out, 4096, 1024, 1024);
}

// Round 3
// 305.003 us; speedup vs baseline: 1.2517x; 1.2517x over previous
//
#include <hip/hip_runtime.h>
#include <hip/hip_bf16.h>

// B=2, T=2048, C=1024, H=16, HD=64, R=32, LORA_SCALE=0.5. f32 I/O, bf16 MFMA.
//   convert_all: all params+x -> bf16 ws
//   t1 = 0.5 * x @ la_attn^T                       (lora_t)
//   qk | vt = x @ w_attn^T + b_attn + t1 @ lb_attn^T  (gemm_lora; V written transposed)
//   y = causal flash attention (no-max softmax, ones-MFMA row sums)
//   t2 = 0.5 * y @ la_proj^T                       (lora_t)
//   out = y @ w_proj^T + b_proj + t2 @ lb_proj^T   (gemm_lora, f32 out)

typedef __attribute__((ext_vector_type(8))) short short8;   // 8 x bf16
typedef __attribute__((ext_vector_type(4))) float float4v;  // MFMA accum

static __device__ __forceinline__ float b2f(ushort u) {
  union { uint i; float f; } v; v.i = ((uint)u) << 16; return v.f;
}
static __device__ __forceinline__ ushort f2b(float f) {
  union { float f; uint i; } v; v.f = f;
  uint i = v.i + 0x7fffu + ((v.i >> 16) & 1u);  // RNE
  return (ushort)(i >> 16);
}
static __device__ __forceinline__ float4v zero4() {
  float4v z = {0.f, 0.f, 0.f, 0.f}; return z;
}
// async global->LDS, 16B per lane; LDS dest = wave-uniform base + lane*16
static __device__ __forceinline__ void glld16(const void* g, void* l) {
  __builtin_amdgcn_global_load_lds((const __attribute__((address_space(1))) void*)g,
                                   (__attribute__((address_space(3))) void*)l,
                                   16, 0, 0);
}

// ---------------- merged f32 -> bf16 conversion (7 segments, float4 chunks)
__global__ __launch_bounds__(256) void convert_all(
    const float* __restrict__ x, const float* __restrict__ wa,
    const float* __restrict__ la, const float* __restrict__ lb,
    const float* __restrict__ wp, const float* __restrict__ lp,
    const float* __restrict__ lq,
    ushort* __restrict__ xb, ushort* __restrict__ wab, ushort* __restrict__ lab,
    ushort* __restrict__ lbb, ushort* __restrict__ wpb, ushort* __restrict__ lpb,
    ushort* __restrict__ lqb) {
  const int stride = gridDim.x * blockDim.x;
  for (int i = blockIdx.x * blockDim.x + threadIdx.x; i < 2146304; i += stride) {
    const float* s; ushort* d; int off;
    if (i < 1048576)      { s = x;  d = xb;  off = i; }
    else if (i < 1835008) { s = wa; d = wab; off = i - 1048576; }
    else if (i < 1843200) { s = la; d = lab; off = i - 1835008; }
    else if (i < 1867776) { s = lb; d = lbb; off = i - 1843200; }
    else if (i < 2129920) { s = wp; d = wpb; off = i - 1867776; }
    else if (i < 2138112) { s = lp; d = lpb; off = i - 2129920; }
    else                  { s = lq; d = lqb; off = i - 2138112; }
    float4 v = ((const float4*)s)[off];
    union { ushort u[4]; uint2 p; } o;
    o.u[0] = f2b(v.x); o.u[1] = f2b(v.y); o.u[2] = f2b(v.z); o.u[3] = f2b(v.w);
    ((uint2*)d)[off] = o.p;
  }
}

// ---------------- LoRA down: T[m][r] = 0.5 * sum_k X[m][k]*La[r][k]
__global__ __launch_bounds__(256) void lora_t(
    const ushort* __restrict__ X, const ushort* __restrict__ La,
    ushort* __restrict__ T) {
  const int tid = threadIdx.x;
  const int m = blockIdx.x * 8 + (tid >> 5);
  const int r = tid & 31;
  const uint4* xr = (const uint4*)(X + (size_t)m * 1024);
  const uint4* lr = (const uint4*)(La + (size_t)r * 1024);
  float s = 0.f;
#pragma unroll 4
  for (int kk = 0; kk < 128; ++kk) {
    uint4 xv = xr[kk], lv = lr[kk];
    s += b2f((ushort)xv.x) * b2f((ushort)lv.x) + b2f((ushort)(xv.x >> 16)) * b2f((ushort)(lv.x >> 16));
    s += b2f((ushort)xv.y) * b2f((ushort)lv.y) + b2f((ushort)(xv.y >> 16)) * b2f((ushort)(lv.y >> 16));
    s += b2f((ushort)xv.z) * b2f((ushort)lv.z) + b2f((ushort)(xv.z >> 16)) * b2f((ushort)(lv.z >> 16));
    s += b2f((ushort)xv.w) * b2f((ushort)lv.w) + b2f((ushort)(xv.w >> 16)) * b2f((ushort)(lv.w >> 16));
  }
  T[(size_t)m * 32 + r] = f2b(0.5f * s);
}

// ---------------- GEMM + LoRA tail, m97 structure: BK=64, unpadded LDS, glld.
// VSPLIT: n>=2048 columns (the V part of qkv) written transposed to vt[b,h,d,t].
template <bool OUTF32, bool VSPLIT>
__global__ __launch_bounds__(256) void gemm_lora(
    const ushort* __restrict__ A, const ushort* __restrict__ W,
    const float* __restrict__ bias,
    const ushort* __restrict__ T1, const ushort* __restrict__ Lb,
    void* __restrict__ outv, ushort* __restrict__ vt, int K, int ldo) {
  __shared__ __attribute__((aligned(16))) ushort As[128 * 64];
  __shared__ __attribute__((aligned(16))) ushort Ws[128 * 64];
  const int tid = threadIdx.x;
  const int lane = tid & 63, wv = tid >> 6;
  const int l15 = lane & 15, quad = lane >> 4;
  const int m0 = blockIdx.y * 128, n0 = blockIdx.x * 128;
  const int wm = (wv >> 1) * 64, wn = (wv & 1) * 64;
  const int r8 = lane >> 3, c8 = (lane & 7) * 8;

  float4v acc[4][4];
#pragma unroll
  for (int i = 0; i < 4; i++)
#pragma unroll
    for (int j = 0; j < 4; j++) acc[i][j] = zero4();

  const int KT = K >> 6;
  for (int kt = 0; kt < KT; ++kt) {
    const int k0 = kt * 64;
    __syncthreads();
#pragma unroll
    for (int u = 0; u < 4; ++u) {
      int R = wv * 32 + u * 8;
      glld16(A + (size_t)(m0 + R + r8) * K + k0 + c8, &As[R * 64 + lane * 8]);
      glld16(W + (size_t)(n0 + R + r8) * K + k0 + c8, &Ws[R * 64 + lane * 8]);
    }
    __syncthreads();
#pragma unroll
    for (int ks = 0; ks < 2; ++ks) {
      short8 af[4], wf[4];
#pragma unroll
      for (int i = 0; i < 4; i++)
        af[i] = *(const short8*)&As[(wm + i * 16 + l15) * 64 + ks * 32 + quad * 8];
#pragma unroll
      for (int j = 0; j < 4; j++)
        wf[j] = *(const short8*)&Ws[(wn + j * 16 + l15) * 64 + ks * 32 + quad * 8];
#pragma unroll
      for (int i = 0; i < 4; i++)
#pragma unroll
        for (int j = 0; j < 4; j++)
          acc[i][j] = __builtin_amdgcn_mfma_f32_16x16x32_bf16(af[i], wf[j], acc[i][j], 0, 0, 0);
    }
  }
  // LoRA tail: one K=32 tile from T1 (128x32) / Lb (128x32)
  __syncthreads();
#pragma unroll
  for (int c = 0; c < 2; ++c) {
    int ch = tid * 2 + c;                 // 512 chunks = 128 rows x 4 sub8
    int row = ch >> 2, sub = ch & 3;
    *(uint4*)&As[row * 64 + sub * 8] = *(const uint4*)(T1 + (size_t)(m0 + row) * 32 + sub * 8);
    *(uint4*)&Ws[row * 64 + sub * 8] = *(const uint4*)(Lb + (size_t)(n0 + row) * 32 + sub * 8);
  }
  __syncthreads();
  {
    short8 af[4], wf[4];
#pragma unroll
    for (int i = 0; i < 4; i++)
      af[i] = *(const short8*)&As[(wm + i * 16 + l15) * 64 + quad * 8];
#pragma unroll
    for (int j = 0; j < 4; j++)
      wf[j] = *(const short8*)&Ws[(wn + j * 16 + l15) * 64 + quad * 8];
#pragma unroll
    for (int i = 0; i < 4; i++)
#pragma unroll
      for (int j = 0; j < 4; j++)
        acc[i][j] = __builtin_amdgcn_mfma_f32_16x16x32_bf16(af[i], wf[j], acc[i][j], 0, 0, 0);
  }
  // epilogue: C/D row = quad*4 + r, col = l15
#pragma unroll
  for (int i = 0; i < 4; i++) {
    int gm = m0 + wm + i * 16 + quad * 4;
#pragma unroll
    for (int j = 0; j < 4; j++) {
      int gn = n0 + wn + j * 16 + l15;
      float bb = bias[gn];
      if (VSPLIT && n0 >= 2048) {
        int vc = gn - 2048;                       // 0..1023 within (h,d)
        int bb2 = gm >> 11, t = gm & 2047;
        ushort u0 = f2b(acc[i][j][0] + bb), u1 = f2b(acc[i][j][1] + bb);
        ushort u2 = f2b(acc[i][j][2] + bb), u3 = f2b(acc[i][j][3] + bb);
        uint2 pk; pk.x = (uint)u0 | ((uint)u1 << 16); pk.y = (uint)u2 | ((uint)u3 << 16);
        *(uint2*)(vt + ((size_t)bb2 * 1024 + vc) * 2048 + t) = pk;
      } else {
#pragma unroll
        for (int r = 0; r < 4; r++) {
          float val = acc[i][j][r] + bb;
          if (OUTF32) ((float*)outv)[(size_t)(gm + r) * ldo + gn] = val;
          else        ((ushort*)outv)[(size_t)(gm + r) * ldo + gn] = f2b(val);
        }
      }
    }
  }
}

// ---------------- Causal flash attention. 512 thr (8 waves), Q-tile 128 rows.
// qk: [4096][2048] (Q|K per head cols), vt: [2048][2048] = [b*1024+h*64+d][t].
// No-max softmax (inputs bounded): p = exp2(s*0.125*log2e); l via ones-MFMA.
__global__ __launch_bounds__(512) void flash_attn(
    const ushort* __restrict__ qk, const ushort* __restrict__ vt,
    ushort* __restrict__ y) {
  __shared__ __attribute__((aligned(16))) ushort Ks[2][64 * 64];
  __shared__ __attribute__((aligned(16))) ushort Vts[2][64 * 64];
  __shared__ __attribute__((aligned(16))) ushort Ps[8 * 16 * 68];  // Q staging too
  const int tid = threadIdx.x;
  const int lane = tid & 63, wv = tid >> 6;
  const int l15 = lane & 15, quad = lane >> 4;
  const int bid = blockIdx.x;
  const int idx = bid & 255;
  const int bh = idx & 31;
  const int g = idx >> 5;                       // 0..7
  const int qb = (bid < 256) ? (15 - g) : g;    // heavy first; pair sums const
  const int b = bh >> 4, h = bh & 15;
  const ushort* qbase = qk + (size_t)b * 2048 * 2048 + h * 64;
  const ushort* kbase = qk + (size_t)b * 2048 * 2048 + 1024 + h * 64;
  const ushort* vbase = vt + ((size_t)b * 1024 + h * 64) * 2048;
  const int r8 = lane >> 3, c8 = (lane & 7) * 8;

  // stage Q (128x64) into Ps area + prefetch K/V tile 0
#pragma unroll
  for (int u = 0; u < 2; ++u) {
    int R = wv * 16 + u * 8;
    glld16(qbase + (size_t)(qb * 128 + R + r8) * 2048 + c8, &Ps[R * 64 + lane * 8]);
  }
  {
    int R = wv * 8;
    glld16(kbase + (size_t)(R + r8) * 2048 + c8, &Ks[0][R * 64 + lane * 8]);
    glld16(vbase + (size_t)(R + r8) * 2048 + c8, &Vts[0][R * 64 + lane * 8]);
  }
  __syncthreads();
  short8 aq0 = *(const short8*)&Ps[(wv * 16 + l15) * 64 + quad * 8];
  short8 aq1 = *(const short8*)&Ps[(wv * 16 + l15) * 64 + 32 + quad * 8];
  __syncthreads();  // all aq reads done; Ps area free for P scatter

  short8 ones;
#pragma unroll
  for (int e = 0; e < 8; e++) ones[e] = (short)0x3F80;  // bf16 1.0

  float4v acc[4];
#pragma unroll
  for (int jt = 0; jt < 4; jt++) acc[jt] = zero4();
  float4v lacc = zero4();
  const int last = 2 * qb + 1;
  const int qrow0 = qb * 128 + wv * 16;
  const int pB = wv * 16 * 68;

  for (int kb = 0; kb <= last; ++kb) {
    const int cur = kb & 1;
    if (kb < last) {
      const int nb = cur ^ 1;
      const int R = wv * 8;
      glld16(kbase + (size_t)((kb + 1) * 64 + R + r8) * 2048 + c8, &Ks[nb][R * 64 + lane * 8]);
      glld16(vbase + (size_t)(R + r8) * 2048 + (kb + 1) * 64 + c8, &Vts[nb][R * 64 + lane * 8]);
    }
    // S = Q K^T
    float4v s[4];
#pragma unroll
    for (int j = 0; j < 4; ++j) {
      short8 bk0 = *(const short8*)&Ks[cur][(j * 16 + l15) * 64 + quad * 8];
      short8 bk1 = *(const short8*)&Ks[cur][(j * 16 + l15) * 64 + 32 + quad * 8];
      s[j] = zero4();
      s[j] = __builtin_amdgcn_mfma_f32_16x16x32_bf16(aq0, bk0, s[j], 0, 0, 0);
      s[j] = __builtin_amdgcn_mfma_f32_16x16x32_bf16(aq1, bk1, s[j], 0, 0, 0);
    }
    if (kb * 64 + 63 > qrow0) {  // wave-uniform: only near-diagonal tiles mask
#pragma unroll
      for (int j = 0; j < 4; ++j) {
        int key = kb * 64 + j * 16 + l15;
#pragma unroll
        for (int r = 0; r < 4; ++r)
          if (key > qrow0 + quad * 4 + r) s[j][r] = -1e30f;
      }
    }
    // p = exp2(s * 0.125*log2e), truncated bf16 into Ps (wave-private)
#pragma unroll
    for (int j = 0; j < 4; ++j)
#pragma unroll
      for (int r = 0; r < 4; ++r) {
        float p = exp2f(s[j][r] * 0.18033688f);
        union { float f; uint i; } u; u.f = p;
        Ps[pB + (quad * 4 + r) * 68 + j * 16 + l15] = (ushort)(u.i >> 16);
      }
    // O += P V ; l += P 1  (same C-layout rows)
#pragma unroll
    for (int kt2 = 0; kt2 < 2; ++kt2) {
      short8 pa = *(const short8*)&Ps[pB + l15 * 68 + kt2 * 32 + quad * 8];
      lacc = __builtin_amdgcn_mfma_f32_16x16x32_bf16(pa, ones, lacc, 0, 0, 0);
#pragma unroll
      for (int jt = 0; jt < 4; ++jt) {
        short8 vb = *(const short8*)&Vts[cur][(jt * 16 + l15) * 64 + kt2 * 32 + quad * 8];
        acc[jt] = __builtin_amdgcn_mfma_f32_16x16x32_bf16(pa, vb, acc[jt], 0, 0, 0);
      }
    }
    __syncthreads();  // drains prefetch glld + protects K/V buffer reuse
  }
#pragma unroll
  for (int r = 0; r < 4; ++r) {
    float inv = __builtin_amdgcn_rcpf(lacc[r]);
    int t = qb * 128 + wv * 16 + quad * 4 + r;
#pragma unroll
    for (int jt = 0; jt < 4; ++jt)
      y[(size_t)(b * 2048 + t) * 1024 + h * 64 + jt * 16 + l15] = f2b(acc[jt][r] * inv);
  }
}

extern "C" void kernel_launch(void* const* d_in, const int* in_sizes, int n_in,
                              void* d_out, int out_size, void* d_ws, size_t ws_size,
                              hipStream_t stream) {
  const float* x       = (const float*)d_in[0];
  const float* w_attn  = (const float*)d_in[1];
  const float* b_attn  = (const float*)d_in[2];
  const float* la_attn = (const float*)d_in[3];
  const float* lb_attn = (const float*)d_in[4];
  const float* w_proj  = (const float*)d_in[5];
  const float* b_proj  = (const float*)d_in[6];
  const float* la_proj = (const float*)d_in[7];
  const float* lb_proj = (const float*)d_in[8];

  ushort* p = (ushort*)d_ws;
  ushort* xb   = p; p += (size_t)4096 * 1024;
  ushort* wab  = p; p += (size_t)3072 * 1024;
  ushort* lab  = p; p += (size_t)32 * 1024;
  ushort* lbb  = p; p += (size_t)3072 * 32;
  ushort* wpb  = p; p += (size_t)1024 * 1024;
  ushort* lpb  = p; p += (size_t)32 * 1024;
  ushort* lqb  = p; p += (size_t)1024 * 32;
  ushort* t1b  = p; p += (size_t)4096 * 32;
  ushort* t2b  = p; p += (size_t)4096 * 32;
  ushort* qkb  = p; p += (size_t)4096 * 2048;   // Q|K halves
  ushort* vtb  = p; p += (size_t)2048 * 2048;   // V transposed [b*1024+h*64+d][t]
  ushort* yb   = p; p += (size_t)4096 * 1024;

  convert_all<<<dim3(2048), dim3(256), 0, stream>>>(
      x, w_attn, la_attn, lb_attn, w_proj, la_proj, lb_proj,
      xb, wab, lab, lbb, wpb, lpb, lqb);
  lora_t<<<dim3(512), dim3(256), 0, stream>>>(xb, lab, t1b);
  gemm_lora<false, true><<<dim3(24, 32), dim3(256), 0, stream>>>(
      xb, wab, b_attn, t1b, lbb, qkb, vtb, 1024, 2048);
  flash_attn<<<dim3(512), dim3(512), 0, stream>>>(qkb, vtb, yb);
  lora_t<<<dim3(512), dim3(256), 0, stream>>>(yb, lpb, t2b);
  gemm_lora<true, false><<<dim3(8, 32), dim3(256), 0, stream>>>(
      yb, wpb, b_proj, t2b, lqb, d_out, nullptr, 1024, 1024);
}

// Round 4
// 284.494 us; speedup vs baseline: 1.3419x; 1.0721x over previous
//
#include <hip/hip_runtime.h>
#include <hip/hip_bf16.h>

// B=2, T=2048, C=1024, H=16, HD=64, R=32, LORA_SCALE=0.5. f32 I/O, bf16 MFMA.
//   convert_all: all params+x -> bf16 ws
//   t1 = 0.5 * x @ la_attn^T                       (lora_t)
//   qk | vt = x @ w_attn^T + b_attn + t1 @ lb_attn^T  (gemm_lora; V transposed)
//   y = causal flash attention (no-max softmax, ones-MFMA row sums)
//   t2 = 0.5 * y @ la_proj^T                       (lora_t)
//   out = y @ w_proj^T + b_proj + t2 @ lb_proj^T   (gemm_lora, f32 out)

typedef __attribute__((ext_vector_type(8))) short short8;   // 8 x bf16
typedef __attribute__((ext_vector_type(4))) float float4v;  // MFMA accum

static __device__ __forceinline__ float b2f(ushort u) {
  union { uint i; float f; } v; v.i = ((uint)u) << 16; return v.f;
}
static __device__ __forceinline__ ushort f2b(float f) {
  union { float f; uint i; } v; v.f = f;
  uint i = v.i + 0x7fffu + ((v.i >> 16) & 1u);  // RNE
  return (ushort)(i >> 16);
}
static __device__ __forceinline__ float4v zero4() {
  float4v z = {0.f, 0.f, 0.f, 0.f}; return z;
}
// async global->LDS; HW dest = wave-uniform LDS base + lane*16
static __device__ __forceinline__ void glld16(const void* g, void* l) {
  __builtin_amdgcn_global_load_lds((const __attribute__((address_space(1))) void*)g,
                                   (__attribute__((address_space(3))) void*)l,
                                   16, 0, 0);
}

// ---------------- merged f32 -> bf16 conversion (7 segments, float4 chunks)
__global__ __launch_bounds__(256) void convert_all(
    const float* __restrict__ x, const float* __restrict__ wa,
    const float* __restrict__ la, const float* __restrict__ lb,
    const float* __restrict__ wp, const float* __restrict__ lp,
    const float* __restrict__ lq,
    ushort* __restrict__ xb, ushort* __restrict__ wab, ushort* __restrict__ lab,
    ushort* __restrict__ lbb, ushort* __restrict__ wpb, ushort* __restrict__ lpb,
    ushort* __restrict__ lqb) {
  const int stride = gridDim.x * blockDim.x;
  for (int i = blockIdx.x * blockDim.x + threadIdx.x; i < 2146304; i += stride) {
    const float* s; ushort* d; int off;
    if (i < 1048576)      { s = x;  d = xb;  off = i; }
    else if (i < 1835008) { s = wa; d = wab; off = i - 1048576; }
    else if (i < 1843200) { s = la; d = lab; off = i - 1835008; }
    else if (i < 1867776) { s = lb; d = lbb; off = i - 1843200; }
    else if (i < 2129920) { s = wp; d = wpb; off = i - 1867776; }
    else if (i < 2138112) { s = lp; d = lpb; off = i - 2129920; }
    else                  { s = lq; d = lqb; off = i - 2138112; }
    float4 v = ((const float4*)s)[off];
    union { ushort u[4]; uint2 p; } o;
    o.u[0] = f2b(v.x); o.u[1] = f2b(v.y); o.u[2] = f2b(v.z); o.u[3] = f2b(v.w);
    ((uint2*)d)[off] = o.p;
  }
}

// ---------------- LoRA down: T[m][r] = 0.5 * sum_k X[m][k]*La[r][k]
__global__ __launch_bounds__(256) void lora_t(
    const ushort* __restrict__ X, const ushort* __restrict__ La,
    ushort* __restrict__ T) {
  const int tid = threadIdx.x;
  const int m = blockIdx.x * 8 + (tid >> 5);
  const int r = tid & 31;
  const uint4* xr = (const uint4*)(X + (size_t)m * 1024);
  const uint4* lr = (const uint4*)(La + (size_t)r * 1024);
  float s = 0.f;
#pragma unroll 4
  for (int kk = 0; kk < 128; ++kk) {
    uint4 xv = xr[kk], lv = lr[kk];
    s += b2f((ushort)xv.x) * b2f((ushort)lv.x) + b2f((ushort)(xv.x >> 16)) * b2f((ushort)(lv.x >> 16));
    s += b2f((ushort)xv.y) * b2f((ushort)lv.y) + b2f((ushort)(xv.y >> 16)) * b2f((ushort)(lv.y >> 16));
    s += b2f((ushort)xv.z) * b2f((ushort)lv.z) + b2f((ushort)(xv.z >> 16)) * b2f((ushort)(lv.z >> 16));
    s += b2f((ushort)xv.w) * b2f((ushort)lv.w) + b2f((ushort)(xv.w >> 16)) * b2f((ushort)(lv.w >> 16));
  }
  T[(size_t)m * 32 + r] = f2b(0.5f * s);
}

// ---------------- GEMM + LoRA tail. 128x128 tile, BK=32, DOUBLE-BUFFERED LDS
// with prefetch-during-compute (one barrier/iter). XCD m-band swizzle:
// by = (L%8)*4 + (L>>3)/NBX keeps each XCD's A-band (1 MB) L2-resident.
// LoRA tail = iteration KT, sourcing T1/Lb (128x32 = exactly one buffer).
template <bool OUTF32, bool VSPLIT, int NBX>
__global__ __launch_bounds__(256) void gemm_lora(
    const ushort* __restrict__ A, const ushort* __restrict__ W,
    const float* __restrict__ bias,
    const ushort* __restrict__ T1, const ushort* __restrict__ Lb,
    void* __restrict__ outv, ushort* __restrict__ vt, int K, int ldo) {
  __shared__ __attribute__((aligned(16))) ushort As[2][128 * 32];  // 8 KB each
  __shared__ __attribute__((aligned(16))) ushort Ws[2][128 * 32];
  const int tid = threadIdx.x;
  const int lane = tid & 63, wv = tid >> 6;
  const int l15 = lane & 15, quad = lane >> 4;
  const int L = blockIdx.x;
  const int x8 = L & 7, q = L >> 3;
  const int bx = q % NBX;
  const int by = x8 * 4 + q / NBX;   // nby = 32 always here
  const int m0 = by * 128, n0 = bx * 128;
  const int wm = (wv >> 1) * 64, wn = (wv & 1) * 64;
  const int r4 = lane >> 2, c4 = (lane & 3) * 8;  // 16 rows x 64B per glld16
  const int KT = K >> 5;

  float4v acc[4][4];
#pragma unroll
  for (int i = 0; i < 4; i++)
#pragma unroll
    for (int j = 0; j < 4; j++) acc[i][j] = zero4();

  // stage K-tile t (t==KT -> LoRA tile from T1/Lb) into buffer buf
  auto stage = [&](int t, int buf) {
    const ushort* sA; const ushort* sW; int ld, k0;
    if (t < KT) { sA = A; sW = W; ld = K; k0 = t * 32; }
    else        { sA = T1; sW = Lb; ld = 32; k0 = 0; }
#pragma unroll
    for (int u = 0; u < 2; ++u) {
      int R = wv * 32 + u * 16;
      glld16(sA + (size_t)(m0 + R + r4) * ld + k0 + c4, &As[buf][R * 32]);
      glld16(sW + (size_t)(n0 + R + r4) * ld + k0 + c4, &Ws[buf][R * 32]);
    }
  };

  stage(0, 0);
  for (int t = 0; t <= KT; ++t) {
    __syncthreads();                     // drains stage(t) vmcnt + prev reads
    if (t < KT) stage(t + 1, (t + 1) & 1);
    const int b = t & 1;
    short8 af[4], wf[4];
#pragma unroll
    for (int i = 0; i < 4; i++)
      af[i] = *(const short8*)&As[b][(wm + i * 16 + l15) * 32 + quad * 8];
#pragma unroll
    for (int j = 0; j < 4; j++)
      wf[j] = *(const short8*)&Ws[b][(wn + j * 16 + l15) * 32 + quad * 8];
#pragma unroll
    for (int i = 0; i < 4; i++)
#pragma unroll
      for (int j = 0; j < 4; j++)
        acc[i][j] = __builtin_amdgcn_mfma_f32_16x16x32_bf16(af[i], wf[j], acc[i][j], 0, 0, 0);
  }

  // epilogue: C/D row = quad*4 + r, col = l15
#pragma unroll
  for (int i = 0; i < 4; i++) {
    int gm = m0 + wm + i * 16 + quad * 4;
#pragma unroll
    for (int j = 0; j < 4; j++) {
      int gn = n0 + wn + j * 16 + l15;
      float bb = bias[gn];
      if (VSPLIT && n0 >= 2048) {
        int vc = gn - 2048;                       // 0..1023 within (h,d)
        int bb2 = gm >> 11, t = gm & 2047;
        ushort u0 = f2b(acc[i][j][0] + bb), u1 = f2b(acc[i][j][1] + bb);
        ushort u2 = f2b(acc[i][j][2] + bb), u3 = f2b(acc[i][j][3] + bb);
        uint2 pk; pk.x = (uint)u0 | ((uint)u1 << 16); pk.y = (uint)u2 | ((uint)u3 << 16);
        *(uint2*)(vt + ((size_t)bb2 * 1024 + vc) * 2048 + t) = pk;
      } else {
#pragma unroll
        for (int r = 0; r < 4; r++) {
          float val = acc[i][j][r] + bb;
          if (OUTF32) ((float*)outv)[(size_t)(gm + r) * ldo + gn] = val;
          else        ((ushort*)outv)[(size_t)(gm + r) * ldo + gn] = f2b(val);
        }
      }
    }
  }
}

// ---------------- Causal flash attention. 512 thr (8 waves), Q-tile 128 rows.
// qk: [4096][2048] (Q|K per head cols), vt: [2048][2048] = [b*1024+h*64+d][t].
// No-max softmax (inputs bounded): p = exp2(s*0.125*log2e); l via ones-MFMA.
__global__ __launch_bounds__(512) void flash_attn(
    const ushort* __restrict__ qk, const ushort* __restrict__ vt,
    ushort* __restrict__ y) {
  __shared__ __attribute__((aligned(16))) ushort Ks[2][64 * 64];
  __shared__ __attribute__((aligned(16))) ushort Vts[2][64 * 64];
  __shared__ __attribute__((aligned(16))) ushort Ps[8 * 16 * 68];  // Q staging too
  const int tid = threadIdx.x;
  const int lane = tid & 63, wv = tid >> 6;
  const int l15 = lane & 15, quad = lane >> 4;
  const int bid = blockIdx.x;
  const int idx = bid & 255;
  const int bh = idx & 31;
  const int g = idx >> 5;                       // 0..7
  const int qb = (bid < 256) ? (15 - g) : g;    // heavy first; pair sums const
  const int b = bh >> 4, h = bh & 15;
  const ushort* qbase = qk + (size_t)b * 2048 * 2048 + h * 64;
  const ushort* kbase = qk + (size_t)b * 2048 * 2048 + 1024 + h * 64;
  const ushort* vbase = vt + ((size_t)b * 1024 + h * 64) * 2048;
  const int r8 = lane >> 3, c8 = (lane & 7) * 8;

  // stage Q (128x64) into Ps area + prefetch K/V tile 0
#pragma unroll
  for (int u = 0; u < 2; ++u) {
    int R = wv * 16 + u * 8;
    glld16(qbase + (size_t)(qb * 128 + R + r8) * 2048 + c8, &Ps[R * 64]);
  }
  {
    int R = wv * 8;
    glld16(kbase + (size_t)(R + r8) * 2048 + c8, &Ks[0][R * 64]);
    glld16(vbase + (size_t)(R + r8) * 2048 + c8, &Vts[0][R * 64]);
  }
  __syncthreads();
  short8 aq0 = *(const short8*)&Ps[(wv * 16 + l15) * 64 + quad * 8];
  short8 aq1 = *(const short8*)&Ps[(wv * 16 + l15) * 64 + 32 + quad * 8];
  __syncthreads();  // all aq reads done; Ps area free for P scatter

  short8 ones;
#pragma unroll
  for (int e = 0; e < 8; e++) ones[e] = (short)0x3F80;  // bf16 1.0

  float4v acc[4];
#pragma unroll
  for (int jt = 0; jt < 4; jt++) acc[jt] = zero4();
  float4v lacc = zero4();
  const int last = 2 * qb + 1;
  const int qrow0 = qb * 128 + wv * 16;
  const int pB = wv * 16 * 68;

  for (int kb = 0; kb <= last; ++kb) {
    const int cur = kb & 1;
    if (kb < last) {
      const int nb = cur ^ 1;
      const int R = wv * 8;
      glld16(kbase + (size_t)((kb + 1) * 64 + R + r8) * 2048 + c8, &Ks[nb][R * 64]);
      glld16(vbase + (size_t)(R + r8) * 2048 + (kb + 1) * 64 + c8, &Vts[nb][R * 64]);
    }
    // S = Q K^T
    float4v s[4];
#pragma unroll
    for (int j = 0; j < 4; ++j) {
      short8 bk0 = *(const short8*)&Ks[cur][(j * 16 + l15) * 64 + quad * 8];
      short8 bk1 = *(const short8*)&Ks[cur][(j * 16 + l15) * 64 + 32 + quad * 8];
      s[j] = zero4();
      s[j] = __builtin_amdgcn_mfma_f32_16x16x32_bf16(aq0, bk0, s[j], 0, 0, 0);
      s[j] = __builtin_amdgcn_mfma_f32_16x16x32_bf16(aq1, bk1, s[j], 0, 0, 0);
    }
    if (kb * 64 + 63 > qrow0) {  // wave-uniform: only near-diagonal tiles mask
#pragma unroll
      for (int j = 0; j < 4; ++j) {
        int key = kb * 64 + j * 16 + l15;
#pragma unroll
        for (int r = 0; r < 4; ++r)
          if (key > qrow0 + quad * 4 + r) s[j][r] = -1e30f;
      }
    }
    // p = exp2(s * 0.125*log2e), truncated bf16 into Ps (wave-private)
#pragma unroll
    for (int j = 0; j < 4; ++j)
#pragma unroll
      for (int r = 0; r < 4; ++r) {
        float p = exp2f(s[j][r] * 0.18033688f);
        union { float f; uint i; } u; u.f = p;
        Ps[pB + (quad * 4 + r) * 68 + j * 16 + l15] = (ushort)(u.i >> 16);
      }
    // O += P V ; l += P 1  (same C-layout rows)
#pragma unroll
    for (int kt2 = 0; kt2 < 2; ++kt2) {
      short8 pa = *(const short8*)&Ps[pB + l15 * 68 + kt2 * 32 + quad * 8];
      lacc = __builtin_amdgcn_mfma_f32_16x16x32_bf16(pa, ones, lacc, 0, 0, 0);
#pragma unroll
      for (int jt = 0; jt < 4; ++jt) {
        short8 vb = *(const short8*)&Vts[cur][(jt * 16 + l15) * 64 + kt2 * 32 + quad * 8];
        acc[jt] = __builtin_amdgcn_mfma_f32_16x16x32_bf16(pa, vb, acc[jt], 0, 0, 0);
      }
    }
    __syncthreads();  // drains prefetch glld + protects K/V buffer reuse
  }
#pragma unroll
  for (int r = 0; r < 4; ++r) {
    float inv = __builtin_amdgcn_rcpf(lacc[r]);
    int t = qb * 128 + wv * 16 + quad * 4 + r;
#pragma unroll
    for (int jt = 0; jt < 4; ++jt)
      y[(size_t)(b * 2048 + t) * 1024 + h * 64 + jt * 16 + l15] = f2b(acc[jt][r] * inv);
  }
}

extern "C" void kernel_launch(void* const* d_in, const int* in_sizes, int n_in,
                              void* d_out, int out_size, void* d_ws, size_t ws_size,
                              hipStream_t stream) {
  const float* x       = (const float*)d_in[0];
  const float* w_attn  = (const float*)d_in[1];
  const float* b_attn  = (const float*)d_in[2];
  const float* la_attn = (const float*)d_in[3];
  const float* lb_attn = (const float*)d_in[4];
  const float* w_proj  = (const float*)d_in[5];
  const float* b_proj  = (const float*)d_in[6];
  const float* la_proj = (const float*)d_in[7];
  const float* lb_proj = (const float*)d_in[8];

  ushort* p = (ushort*)d_ws;
  ushort* xb   = p; p += (size_t)4096 * 1024;
  ushort* wab  = p; p += (size_t)3072 * 1024;
  ushort* lab  = p; p += (size_t)32 * 1024;
  ushort* lbb  = p; p += (size_t)3072 * 32;
  ushort* wpb  = p; p += (size_t)1024 * 1024;
  ushort* lpb  = p; p += (size_t)32 * 1024;
  ushort* lqb  = p; p += (size_t)1024 * 32;
  ushort* t1b  = p; p += (size_t)4096 * 32;
  ushort* t2b  = p; p += (size_t)4096 * 32;
  ushort* qkb  = p; p += (size_t)4096 * 2048;   // Q|K halves
  ushort* vtb  = p; p += (size_t)2048 * 2048;   // V transposed [b*1024+h*64+d][t]
  ushort* yb   = p; p += (size_t)4096 * 1024;

  convert_all<<<dim3(2048), dim3(256), 0, stream>>>(
      x, w_attn, la_attn, lb_attn, w_proj, la_proj, lb_proj,
      xb, wab, lab, lbb, wpb, lpb, lqb);
  lora_t<<<dim3(512), dim3(256), 0, stream>>>(xb, lab, t1b);
  gemm_lora<false, true, 24><<<dim3(768), dim3(256), 0, stream>>>(
      xb, wab, b_attn, t1b, lbb, qkb, vtb, 1024, 2048);
  flash_attn<<<dim3(512), dim3(512), 0, stream>>>(qkb, vtb, yb);
  lora_t<<<dim3(512), dim3(256), 0, stream>>>(yb, lpb, t2b);
  gemm_lora<true, false, 8><<<dim3(256), dim3(256), 0, stream>>>(
      yb, wpb, b_proj, t2b, lqb, d_out, nullptr, 1024, 1024);
}

// Round 6
// 282.208 us; speedup vs baseline: 1.3528x; 1.0081x over previous
//
#include <hip/hip_runtime.h>
#include <hip/hip_bf16.h>

// B=2, T=2048, C=1024, H=16, HD=64, R=32, LORA_SCALE=0.5. f32 I/O, bf16 MFMA.
//   convert_all: all params+x -> bf16 ws
//   t1 = 0.5 * x @ la_attn^T                       (lora_t)
//   qk | vt = x @ w_attn^T + b_attn + t1 @ lb_attn^T  (gemm_lora; V transposed,
//             q columns pre-scaled by 0.125*log2(e) for exp2-softmax)
//   y = causal flash attention (no-max softmax, ones-MFMA row sums)
//   t2 = 0.5 * y @ la_proj^T                       (lora_t)
//   out = y @ w_proj^T + b_proj + t2 @ lb_proj^T   (gemm_lora, f32 out)

typedef __attribute__((ext_vector_type(8))) short short8;   // 8 x bf16
typedef __attribute__((ext_vector_type(4))) float float4v;  // MFMA accum

#define QSCALE 0.18033688011112292f  // 0.125 * log2(e)

static __device__ __forceinline__ float b2f(ushort u) {
  union { uint i; float f; } v; v.i = ((uint)u) << 16; return v.f;
}
static __device__ __forceinline__ ushort f2b(float f) {
  union { float f; uint i; } v; v.f = f;
  uint i = v.i + 0x7fffu + ((v.i >> 16) & 1u);  // RNE
  return (ushort)(i >> 16);
}
static __device__ __forceinline__ float4v zero4() {
  float4v z = {0.f, 0.f, 0.f, 0.f}; return z;
}
// async global->LDS; HW dest = wave-uniform LDS base + lane*16
static __device__ __forceinline__ void glld16(const void* g, void* l) {
  __builtin_amdgcn_global_load_lds((const __attribute__((address_space(1))) void*)g,
                                   (__attribute__((address_space(3))) void*)l,
                                   16, 0, 0);
}

// ---------------- merged f32 -> bf16 conversion (7 segments, float4 chunks)
__global__ __launch_bounds__(256) void convert_all(
    const float* __restrict__ x, const float* __restrict__ wa,
    const float* __restrict__ la, const float* __restrict__ lb,
    const float* __restrict__ wp, const float* __restrict__ lp,
    const float* __restrict__ lq,
    ushort* __restrict__ xb, ushort* __restrict__ wab, ushort* __restrict__ lab,
    ushort* __restrict__ lbb, ushort* __restrict__ wpb, ushort* __restrict__ lpb,
    ushort* __restrict__ lqb) {
  const int stride = gridDim.x * blockDim.x;
  for (int i = blockIdx.x * blockDim.x + threadIdx.x; i < 2146304; i += stride) {
    const float* s; ushort* d; int off;
    if (i < 1048576)      { s = x;  d = xb;  off = i; }
    else if (i < 1835008) { s = wa; d = wab; off = i - 1048576; }
    else if (i < 1843200) { s = la; d = lab; off = i - 1835008; }
    else if (i < 1867776) { s = lb; d = lbb; off = i - 1843200; }
    else if (i < 2129920) { s = wp; d = wpb; off = i - 1867776; }
    else if (i < 2138112) { s = lp; d = lpb; off = i - 2129920; }
    else                  { s = lq; d = lqb; off = i - 2138112; }
    float4 v = ((const float4*)s)[off];
    union { ushort u[4]; uint2 p; } o;
    o.u[0] = f2b(v.x); o.u[1] = f2b(v.y); o.u[2] = f2b(v.z); o.u[3] = f2b(v.w);
    ((uint2*)d)[off] = o.p;
  }
}

// ---------------- LoRA down: T[m][r] = 0.5 * sum_k X[m][k]*La[r][k]
__global__ __launch_bounds__(256) void lora_t(
    const ushort* __restrict__ X, const ushort* __restrict__ La,
    ushort* __restrict__ T) {
  const int tid = threadIdx.x;
  const int m = blockIdx.x * 8 + (tid >> 5);
  const int r = tid & 31;
  const uint4* xr = (const uint4*)(X + (size_t)m * 1024);
  const uint4* lr = (const uint4*)(La + (size_t)r * 1024);
  float s = 0.f;
#pragma unroll 4
  for (int kk = 0; kk < 128; ++kk) {
    uint4 xv = xr[kk], lv = lr[kk];
    s += b2f((ushort)xv.x) * b2f((ushort)lv.x) + b2f((ushort)(xv.x >> 16)) * b2f((ushort)(lv.x >> 16));
    s += b2f((ushort)xv.y) * b2f((ushort)lv.y) + b2f((ushort)(xv.y >> 16)) * b2f((ushort)(lv.y >> 16));
    s += b2f((ushort)xv.z) * b2f((ushort)lv.z) + b2f((ushort)(xv.z >> 16)) * b2f((ushort)(lv.z >> 16));
    s += b2f((ushort)xv.w) * b2f((ushort)lv.w) + b2f((ushort)(xv.w >> 16)) * b2f((ushort)(lv.w >> 16));
  }
  T[(size_t)m * 32 + r] = f2b(0.5f * s);
}

// ---------------- GEMM + LoRA tail. 128x128 tile, BK=32, double-buffered LDS
// with prefetch-during-compute. XCD m-band swizzle. LoRA tail = iteration KT.
// VSPLIT: q cols (n<1024) scaled by QSCALE; v cols (n>=2048) written transposed.
template <bool OUTF32, bool VSPLIT, int NBX>
__global__ __launch_bounds__(256) void gemm_lora(
    const ushort* __restrict__ A, const ushort* __restrict__ W,
    const float* __restrict__ bias,
    const ushort* __restrict__ T1, const ushort* __restrict__ Lb,
    void* __restrict__ outv, ushort* __restrict__ vt, int K, int ldo) {
  __shared__ __attribute__((aligned(16))) ushort As[2][128 * 32];  // 8 KB each
  __shared__ __attribute__((aligned(16))) ushort Ws[2][128 * 32];
  const int tid = threadIdx.x;
  const int lane = tid & 63, wv = tid >> 6;
  const int l15 = lane & 15, quad = lane >> 4;
  const int L = blockIdx.x;
  const int x8 = L & 7, q = L >> 3;
  const int bx = q % NBX;
  const int by = x8 * 4 + q / NBX;   // nby = 32 always here
  const int m0 = by * 128, n0 = bx * 128;
  const int wm = (wv >> 1) * 64, wn = (wv & 1) * 64;
  const int r4 = lane >> 2, c4 = (lane & 3) * 8;  // 16 rows x 64B per glld16
  const int KT = K >> 5;

  float4v acc[4][4];
#pragma unroll
  for (int i = 0; i < 4; i++)
#pragma unroll
    for (int j = 0; j < 4; j++) acc[i][j] = zero4();

  auto stage = [&](int t, int buf) {
    const ushort* sA; const ushort* sW; int ld, k0;
    if (t < KT) { sA = A; sW = W; ld = K; k0 = t * 32; }
    else        { sA = T1; sW = Lb; ld = 32; k0 = 0; }
#pragma unroll
    for (int u = 0; u < 2; ++u) {
      int R = wv * 32 + u * 16;
      glld16(sA + (size_t)(m0 + R + r4) * ld + k0 + c4, &As[buf][R * 32]);
      glld16(sW + (size_t)(n0 + R + r4) * ld + k0 + c4, &Ws[buf][R * 32]);
    }
  };

  stage(0, 0);
  for (int t = 0; t <= KT; ++t) {
    __syncthreads();                     // drains stage(t) vmcnt + prev reads
    if (t < KT) stage(t + 1, (t + 1) & 1);
    const int b = t & 1;
    short8 af[4], wf[4];
#pragma unroll
    for (int i = 0; i < 4; i++)
      af[i] = *(const short8*)&As[b][(wm + i * 16 + l15) * 32 + quad * 8];
#pragma unroll
    for (int j = 0; j < 4; j++)
      wf[j] = *(const short8*)&Ws[b][(wn + j * 16 + l15) * 32 + quad * 8];
#pragma unroll
    for (int i = 0; i < 4; i++)
#pragma unroll
      for (int j = 0; j < 4; j++)
        acc[i][j] = __builtin_amdgcn_mfma_f32_16x16x32_bf16(af[i], wf[j], acc[i][j], 0, 0, 0);
  }

  const float qsc = (VSPLIT && n0 < 1024) ? QSCALE : 1.0f;
  // epilogue: C/D row = quad*4 + r, col = l15
#pragma unroll
  for (int i = 0; i < 4; i++) {
    int gm = m0 + wm + i * 16 + quad * 4;
#pragma unroll
    for (int j = 0; j < 4; j++) {
      int gn = n0 + wn + j * 16 + l15;
      float bb = bias[gn];
      if (VSPLIT && n0 >= 2048) {
        int vc = gn - 2048;                       // 0..1023 within (h,d)
        int bb2 = gm >> 11, t = gm & 2047;
        ushort u0 = f2b(acc[i][j][0] + bb), u1 = f2b(acc[i][j][1] + bb);
        ushort u2 = f2b(acc[i][j][2] + bb), u3 = f2b(acc[i][j][3] + bb);
        uint2 pk; pk.x = (uint)u0 | ((uint)u1 << 16); pk.y = (uint)u2 | ((uint)u3 << 16);
        *(uint2*)(vt + ((size_t)bb2 * 1024 + vc) * 2048 + t) = pk;
      } else {
#pragma unroll
        for (int r = 0; r < 4; r++) {
          float val = (acc[i][j][r] + bb) * qsc;
          if (OUTF32) ((float*)outv)[(size_t)(gm + r) * ldo + gn] = val;
          else        ((ushort*)outv)[(size_t)(gm + r) * ldo + gn] = f2b(val);
        }
      }
    }
  }
}

// ---------------- Causal flash attention. 256 thr (4 waves x 32 q-rows),
// Q-tile 128 rows, K/V tiles 64 keys, double-buffered, col-rotated LDS.
// Write: LDS[row][c] = G[row][(c + 8*(row%8)) & 63]  (rotation at glld time)
// Read:  logical k lives at LDS col c = (k - 8*(row%8)) & 63   <-- sign fixed!
// q pre-scaled by QSCALE -> p = exp2(s); row sums l via ones-MFMA.
__global__ __launch_bounds__(256) void flash_attn(
    const ushort* __restrict__ qk, const ushort* __restrict__ vt,
    ushort* __restrict__ y) {
  __shared__ __attribute__((aligned(16))) ushort Ks[2][64 * 64];
  __shared__ __attribute__((aligned(16))) ushort Vts[2][64 * 64];
  __shared__ __attribute__((aligned(16))) ushort Ps[4 * 32 * 68];  // Q staging too
  const int tid = threadIdx.x;
  const int lane = tid & 63, wv = tid >> 6;
  const int l15 = lane & 15, quad = lane >> 4;
  const int bid = blockIdx.x;
  const int idx = bid & 255;
  const int bh = idx & 31;
  const int g = idx >> 5;                       // 0..7
  const int qb = (bid < 256) ? (15 - g) : g;    // heavy first
  const int b = bh >> 4, h = bh & 15;
  const ushort* qbase = qk + (size_t)b * 2048 * 2048 + h * 64;
  const ushort* kbase = qk + (size_t)b * 2048 * 2048 + 1024 + h * 64;
  const ushort* vbase = vt + ((size_t)b * 1024 + h * 64) * 2048;
  const int r8 = lane >> 3, c8 = (lane & 7) * 8;
  const int rotc = (c8 + r8 * 8) & 63;          // rotated source column (write)
  // READ columns: invert the write rotation -> (k - 8*(row%8)) & 63, row%8 = l15&7
  const int colk0 = (quad * 8 + 64 - 8 * (l15 & 7)) & 63;
  const int colk1 = (colk0 + 32) & 63;

  // stage Q (128x64, rotated) into Ps area; prefetch K/V tile 0
#pragma unroll
  for (int u = 0; u < 4; ++u) {
    int R = wv * 32 + u * 8;
    glld16(qbase + (size_t)(qb * 128 + R + r8) * 2048 + rotc, &Ps[R * 64]);
  }
#pragma unroll
  for (int u = 0; u < 2; ++u) {
    int R = wv * 16 + u * 8;
    glld16(kbase + (size_t)(R + r8) * 2048 + rotc, &Ks[0][R * 64]);
    glld16(vbase + (size_t)(R + r8) * 2048 + rotc, &Vts[0][R * 64]);
  }
  __syncthreads();
  short8 aq[2][2];
#pragma unroll
  for (int i = 0; i < 2; ++i) {
    const int w = wv * 32 + i * 16 + l15;
    aq[i][0] = *(const short8*)&Ps[w * 64 + colk0];
    aq[i][1] = *(const short8*)&Ps[w * 64 + colk1];
  }
  __syncthreads();  // aq reads done; Ps area free for P scatter

  short8 ones;
#pragma unroll
  for (int e = 0; e < 8; e++) ones[e] = (short)0x3F80;  // bf16 1.0

  float4v acc[2][4];
  float4v lacc[2];
#pragma unroll
  for (int i = 0; i < 2; ++i) {
    lacc[i] = zero4();
#pragma unroll
    for (int jt = 0; jt < 4; jt++) acc[i][jt] = zero4();
  }
  const int last = 2 * qb + 1;
  const int pB = wv * 32 * 68;

  for (int kb = 0; kb <= last; ++kb) {
    const int cur = kb & 1;
    if (kb < last) {
      const int nb = cur ^ 1;
#pragma unroll
      for (int u = 0; u < 2; ++u) {
        int R = wv * 16 + u * 8;
        glld16(kbase + (size_t)((kb + 1) * 64 + R + r8) * 2048 + rotc, &Ks[nb][R * 64]);
        glld16(vbase + (size_t)(R + r8) * 2048 + (kb + 1) * 64 + rotc, &Vts[nb][R * 64]);
      }
    }
    // S = Q K^T (K-frags reused across both row-tiles)
    float4v s[2][4];
#pragma unroll
    for (int i = 0; i < 2; ++i)
#pragma unroll
      for (int j = 0; j < 4; ++j) s[i][j] = zero4();
#pragma unroll
    for (int j = 0; j < 4; ++j) {
      short8 bk0 = *(const short8*)&Ks[cur][(j * 16 + l15) * 64 + colk0];
      short8 bk1 = *(const short8*)&Ks[cur][(j * 16 + l15) * 64 + colk1];
#pragma unroll
      for (int i = 0; i < 2; ++i) {
        s[i][j] = __builtin_amdgcn_mfma_f32_16x16x32_bf16(aq[i][0], bk0, s[i][j], 0, 0, 0);
        s[i][j] = __builtin_amdgcn_mfma_f32_16x16x32_bf16(aq[i][1], bk1, s[i][j], 0, 0, 0);
      }
    }
    // causal mask (only near-diagonal tiles; wave-uniform branch per row-tile)
#pragma unroll
    for (int i = 0; i < 2; ++i) {
      const int qrow_i = qb * 128 + wv * 32 + i * 16;
      if (kb * 64 + 63 > qrow_i) {
#pragma unroll
        for (int j = 0; j < 4; ++j) {
          int key = kb * 64 + j * 16 + l15;
#pragma unroll
          for (int r = 0; r < 4; ++r)
            if (key > qrow_i + quad * 4 + r) s[i][j][r] = -1e30f;
        }
      }
    }
    // P = exp2(s), truncated bf16, into wave-private Ps (conflict-free layout)
#pragma unroll
    for (int i = 0; i < 2; ++i)
#pragma unroll
      for (int j = 0; j < 4; ++j)
#pragma unroll
        for (int r = 0; r < 4; ++r) {
          float pv = exp2f(s[i][j][r]);
          union { float f; uint u; } cv; cv.f = pv;
          Ps[pB + (i * 16 + quad * 4 + r) * 68 + j * 16 + l15] = (ushort)(cv.u >> 16);
        }
    // O += P V ; l += P 1 (V-frags reused across both row-tiles)
#pragma unroll
    for (int kt2 = 0; kt2 < 2; ++kt2) {
      const int vcol = kt2 ? colk1 : colk0;
      short8 pa[2];
#pragma unroll
      for (int i = 0; i < 2; ++i) {
        pa[i] = *(const short8*)&Ps[pB + (i * 16 + l15) * 68 + kt2 * 32 + quad * 8];
        lacc[i] = __builtin_amdgcn_mfma_f32_16x16x32_bf16(pa[i], ones, lacc[i], 0, 0, 0);
      }
#pragma unroll
      for (int jt = 0; jt < 4; ++jt) {
        short8 vb = *(const short8*)&Vts[cur][(jt * 16 + l15) * 64 + vcol];
#pragma unroll
        for (int i = 0; i < 2; ++i)
          acc[i][jt] = __builtin_amdgcn_mfma_f32_16x16x32_bf16(pa[i], vb, acc[i][jt], 0, 0, 0);
      }
    }
    __syncthreads();  // drains prefetch glld + protects K/V + Ps reuse
  }
#pragma unroll
  for (int i = 0; i < 2; ++i)
#pragma unroll
    for (int r = 0; r < 4; ++r) {
      float inv = __builtin_amdgcn_rcpf(lacc[i][r]);
      int t = qb * 128 + wv * 32 + i * 16 + quad * 4 + r;
#pragma unroll
      for (int jt = 0; jt < 4; ++jt)
        y[(size_t)(b * 2048 + t) * 1024 + h * 64 + jt * 16 + l15] =
            f2b(acc[i][jt][r] * inv);
    }
}

extern "C" void kernel_launch(void* const* d_in, const int* in_sizes, int n_in,
                              void* d_out, int out_size, void* d_ws, size_t ws_size,
                              hipStream_t stream) {
  const float* x       = (const float*)d_in[0];
  const float* w_attn  = (const float*)d_in[1];
  const float* b_attn  = (const float*)d_in[2];
  const float* la_attn = (const float*)d_in[3];
  const float* lb_attn = (const float*)d_in[4];
  const float* w_proj  = (const float*)d_in[5];
  const float* b_proj  = (const float*)d_in[6];
  const float* la_proj = (const float*)d_in[7];
  const float* lb_proj = (const float*)d_in[8];

  ushort* p = (ushort*)d_ws;
  ushort* xb   = p; p += (size_t)4096 * 1024;
  ushort* wab  = p; p += (size_t)3072 * 1024;
  ushort* lab  = p; p += (size_t)32 * 1024;
  ushort* lbb  = p; p += (size_t)3072 * 32;
  ushort* wpb  = p; p += (size_t)1024 * 1024;
  ushort* lpb  = p; p += (size_t)32 * 1024;
  ushort* lqb  = p; p += (size_t)1024 * 32;
  ushort* t1b  = p; p += (size_t)4096 * 32;
  ushort* t2b  = p; p += (size_t)4096 * 32;
  ushort* qkb  = p; p += (size_t)4096 * 2048;   // Q|K halves (q pre-scaled)
  ushort* vtb  = p; p += (size_t)2048 * 2048;   // V transposed [b*1024+h*64+d][t]
  ushort* yb   = p; p += (size_t)4096 * 1024;

  convert_all<<<dim3(2048), dim3(256), 0, stream>>>(
      x, w_attn, la_attn, lb_attn, w_proj, la_proj, lb_proj,
      xb, wab, lab, lbb, wpb, lpb, lqb);
  lora_t<<<dim3(512), dim3(256), 0, stream>>>(xb, lab, t1b);
  gemm_lora<false, true, 24><<<dim3(768), dim3(256), 0, stream>>>(
      xb, wab, b_attn, t1b, lbb, qkb, vtb, 1024, 2048);
  flash_attn<<<dim3(512), dim3(256), 0, stream>>>(qkb, vtb, yb);
  lora_t<<<dim3(512), dim3(256), 0, stream>>>(yb, lpb, t2b);
  gemm_lora<true, false, 8><<<dim3(256), dim3(256), 0, stream>>>(
      yb, wpb, b_proj, t2b, lqb, d_out, nullptr, 1024, 1024);
}

// Round 7
// 273.414 us; speedup vs baseline: 1.3963x; 1.0322x over previous
//
#include <hip/hip_runtime.h>
#include <hip/hip_bf16.h>

// B=2, T=2048, C=1024, H=16, HD=64, R=32, LORA_SCALE=0.5. f32 I/O, bf16 MFMA.
//   convert_all: all params+x -> bf16 ws
//   t1 = 0.5 * x @ la_attn^T                       (lora_t)
//   qk | vt = x @ w_attn^T + b_attn + t1 @ lb_attn^T  (gemm_lora; V transposed,
//             q columns pre-scaled by 0.125*log2(e) for exp2-softmax)
//   y = causal flash attention (no-max softmax, ones-MFMA row sums)
//   t2 = 0.5 * y @ la_proj^T                       (lora_t)
//   out = y @ w_proj^T + b_proj + t2 @ lb_proj^T   (gemm_lora, f32 out)

typedef __attribute__((ext_vector_type(8))) short short8;   // 8 x bf16
typedef __attribute__((ext_vector_type(4))) float float4v;  // MFMA accum

#define QSCALE 0.18033688011112292f  // 0.125 * log2(e)

static __device__ __forceinline__ float b2f(ushort u) {
  union { uint i; float f; } v; v.i = ((uint)u) << 16; return v.f;
}
static __device__ __forceinline__ ushort f2b(float f) {
  union { float f; uint i; } v; v.f = f;
  uint i = v.i + 0x7fffu + ((v.i >> 16) & 1u);  // RNE
  return (ushort)(i >> 16);
}
static __device__ __forceinline__ float4v zero4() {
  float4v z = {0.f, 0.f, 0.f, 0.f}; return z;
}
// async global->LDS; HW dest = wave-uniform LDS base + lane*16
static __device__ __forceinline__ void glld16(const void* g, void* l) {
  __builtin_amdgcn_global_load_lds((const __attribute__((address_space(1))) void*)g,
                                   (__attribute__((address_space(3))) void*)l,
                                   16, 0, 0);
}

// ---------------- merged f32 -> bf16 conversion (7 segments, float4 chunks)
__global__ __launch_bounds__(256) void convert_all(
    const float* __restrict__ x, const float* __restrict__ wa,
    const float* __restrict__ la, const float* __restrict__ lb,
    const float* __restrict__ wp, const float* __restrict__ lp,
    const float* __restrict__ lq,
    ushort* __restrict__ xb, ushort* __restrict__ wab, ushort* __restrict__ lab,
    ushort* __restrict__ lbb, ushort* __restrict__ wpb, ushort* __restrict__ lpb,
    ushort* __restrict__ lqb) {
  const int stride = gridDim.x * blockDim.x;
  for (int i = blockIdx.x * blockDim.x + threadIdx.x; i < 2146304; i += stride) {
    const float* s; ushort* d; int off;
    if (i < 1048576)      { s = x;  d = xb;  off = i; }
    else if (i < 1835008) { s = wa; d = wab; off = i - 1048576; }
    else if (i < 1843200) { s = la; d = lab; off = i - 1835008; }
    else if (i < 1867776) { s = lb; d = lbb; off = i - 1843200; }
    else if (i < 2129920) { s = wp; d = wpb; off = i - 1867776; }
    else if (i < 2138112) { s = lp; d = lpb; off = i - 2129920; }
    else                  { s = lq; d = lqb; off = i - 2138112; }
    float4 v = ((const float4*)s)[off];
    union { ushort u[4]; uint2 p; } o;
    o.u[0] = f2b(v.x); o.u[1] = f2b(v.y); o.u[2] = f2b(v.z); o.u[3] = f2b(v.w);
    ((uint2*)d)[off] = o.p;
  }
}

// ---------------- LoRA down: T[m][r] = 0.5 * sum_k X[m][k]*La[r][k]
__global__ __launch_bounds__(256) void lora_t(
    const ushort* __restrict__ X, const ushort* __restrict__ La,
    ushort* __restrict__ T) {
  const int tid = threadIdx.x;
  const int m = blockIdx.x * 8 + (tid >> 5);
  const int r = tid & 31;
  const uint4* xr = (const uint4*)(X + (size_t)m * 1024);
  const uint4* lr = (const uint4*)(La + (size_t)r * 1024);
  float s = 0.f;
#pragma unroll 4
  for (int kk = 0; kk < 128; ++kk) {
    uint4 xv = xr[kk], lv = lr[kk];
    s += b2f((ushort)xv.x) * b2f((ushort)lv.x) + b2f((ushort)(xv.x >> 16)) * b2f((ushort)(lv.x >> 16));
    s += b2f((ushort)xv.y) * b2f((ushort)lv.y) + b2f((ushort)(xv.y >> 16)) * b2f((ushort)(lv.y >> 16));
    s += b2f((ushort)xv.z) * b2f((ushort)lv.z) + b2f((ushort)(xv.z >> 16)) * b2f((ushort)(lv.z >> 16));
    s += b2f((ushort)xv.w) * b2f((ushort)lv.w) + b2f((ushort)(xv.w >> 16)) * b2f((ushort)(lv.w >> 16));
  }
  T[(size_t)m * 32 + r] = f2b(0.5f * s);
}

// ---------------- GEMM + LoRA tail. 128x128 tile, BK=32, double-buffered LDS
// with prefetch-during-compute. XCD m-band swizzle. LoRA tail = iteration KT.
// VSPLIT: q cols (n<1024) scaled by QSCALE; v cols (n>=2048) written transposed.
template <bool OUTF32, bool VSPLIT, int NBX>
__global__ __launch_bounds__(256) void gemm_lora(
    const ushort* __restrict__ A, const ushort* __restrict__ W,
    const float* __restrict__ bias,
    const ushort* __restrict__ T1, const ushort* __restrict__ Lb,
    void* __restrict__ outv, ushort* __restrict__ vt, int K, int ldo) {
  __shared__ __attribute__((aligned(16))) ushort As[2][128 * 32];  // 8 KB each
  __shared__ __attribute__((aligned(16))) ushort Ws[2][128 * 32];
  const int tid = threadIdx.x;
  const int lane = tid & 63, wv = tid >> 6;
  const int l15 = lane & 15, quad = lane >> 4;
  const int L = blockIdx.x;
  const int x8 = L & 7, q = L >> 3;
  const int bx = q % NBX;
  const int by = x8 * 4 + q / NBX;   // nby = 32 always here
  const int m0 = by * 128, n0 = bx * 128;
  const int wm = (wv >> 1) * 64, wn = (wv & 1) * 64;
  const int r4 = lane >> 2, c4 = (lane & 3) * 8;  // 16 rows x 64B per glld16
  const int KT = K >> 5;

  float4v acc[4][4];
#pragma unroll
  for (int i = 0; i < 4; i++)
#pragma unroll
    for (int j = 0; j < 4; j++) acc[i][j] = zero4();

  auto stage = [&](int t, int buf) {
    const ushort* sA; const ushort* sW; int ld, k0;
    if (t < KT) { sA = A; sW = W; ld = K; k0 = t * 32; }
    else        { sA = T1; sW = Lb; ld = 32; k0 = 0; }
#pragma unroll
    for (int u = 0; u < 2; ++u) {
      int R = wv * 32 + u * 16;
      glld16(sA + (size_t)(m0 + R + r4) * ld + k0 + c4, &As[buf][R * 32]);
      glld16(sW + (size_t)(n0 + R + r4) * ld + k0 + c4, &Ws[buf][R * 32]);
    }
  };

  stage(0, 0);
  for (int t = 0; t <= KT; ++t) {
    __syncthreads();                     // drains stage(t) vmcnt + prev reads
    if (t < KT) stage(t + 1, (t + 1) & 1);
    const int b = t & 1;
    short8 af[4], wf[4];
#pragma unroll
    for (int i = 0; i < 4; i++)
      af[i] = *(const short8*)&As[b][(wm + i * 16 + l15) * 32 + quad * 8];
#pragma unroll
    for (int j = 0; j < 4; j++)
      wf[j] = *(const short8*)&Ws[b][(wn + j * 16 + l15) * 32 + quad * 8];
#pragma unroll
    for (int i = 0; i < 4; i++)
#pragma unroll
      for (int j = 0; j < 4; j++)
        acc[i][j] = __builtin_amdgcn_mfma_f32_16x16x32_bf16(af[i], wf[j], acc[i][j], 0, 0, 0);
  }

  const float qsc = (VSPLIT && n0 < 1024) ? QSCALE : 1.0f;
  // epilogue: C/D row = quad*4 + r, col = l15
#pragma unroll
  for (int i = 0; i < 4; i++) {
    int gm = m0 + wm + i * 16 + quad * 4;
#pragma unroll
    for (int j = 0; j < 4; j++) {
      int gn = n0 + wn + j * 16 + l15;
      float bb = bias[gn];
      if (VSPLIT && n0 >= 2048) {
        int vc = gn - 2048;                       // 0..1023 within (h,d)
        int bb2 = gm >> 11, t = gm & 2047;
        ushort u0 = f2b(acc[i][j][0] + bb), u1 = f2b(acc[i][j][1] + bb);
        ushort u2 = f2b(acc[i][j][2] + bb), u3 = f2b(acc[i][j][3] + bb);
        uint2 pk; pk.x = (uint)u0 | ((uint)u1 << 16); pk.y = (uint)u2 | ((uint)u3 << 16);
        *(uint2*)(vt + ((size_t)bb2 * 1024 + vc) * 2048 + t) = pk;
      } else {
#pragma unroll
        for (int r = 0; r < 4; r++) {
          float val = (acc[i][j][r] + bb) * qsc;
          if (OUTF32) ((float*)outv)[(size_t)(gm + r) * ldo + gn] = val;
          else        ((ushort*)outv)[(size_t)(gm + r) * ldo + gn] = f2b(val);
        }
      }
    }
  }
}

// ---------------- Causal flash attention, merged-pair blocks.
// grid 256 = 1 block/CU. Block L: bh = (L&7)*4 + ((L>>3)&3) (XCD-local K/V),
// pair g = L>>5: waves 0-3 -> q-tile 15-g (heavy), waves 4-7 -> q-tile g
// (light), SHARING K/V staging. 512 thr, 32 q-rows/wave.
// K/V LDS: rot = 8*(row&7) (glld-time col rotation, read col k-8*rot).
// Ps (per-wave 32x64, also Q staging): rot2 = 8*((row>>1)&7), same subtract
// convention on write and read. LDS total = 16+16+32 KB = 64 KB exactly.
__global__ __launch_bounds__(512) void flash_attn(
    const ushort* __restrict__ qk, const ushort* __restrict__ vt,
    ushort* __restrict__ y) {
  __shared__ __attribute__((aligned(16))) ushort Ks[2][64 * 64];
  __shared__ __attribute__((aligned(16))) ushort Vts[2][64 * 64];
  __shared__ __attribute__((aligned(16))) ushort Ps[8 * 32 * 64];
  const int tid = threadIdx.x;
  const int lane = tid & 63, wv = tid >> 6;
  const int l15 = lane & 15, quad = lane >> 4;
  const int L = blockIdx.x;
  const int bh = (L & 7) * 4 + ((L >> 3) & 3);
  const int g = L >> 5;
  const int b = bh >> 4, h = bh & 15;
  const int qbH = 15 - g, qbL = g;
  const int qtile = (wv < 4) ? qbH : qbL;
  const int wl = wv & 3;
  const int lastH = 2 * qbH + 1;
  const int lastL = 2 * qbL + 1;
  const ushort* qbase = qk + (size_t)b * 2048 * 2048 + h * 64;
  const ushort* kbase = qk + (size_t)b * 2048 * 2048 + 1024 + h * 64;
  const ushort* vbase = vt + ((size_t)b * 1024 + h * 64) * 2048;
  const int r8 = lane >> 3, c8 = (lane & 7) * 8;
  const int rotKV = (c8 + 8 * r8) & 63;                 // K/V write rotation
  const int colk0 = (quad * 8 + 64 - 8 * (l15 & 7)) & 63;   // K/V read col
  const int colk1 = (colk0 + 32) & 63;
  const int pcol0 = (quad * 8 + 64 - 8 * (l15 >> 1)) & 63;  // Ps read col
  const int pcol1 = (pcol0 + 32) & 63;
  const int pB = wv * 2048;                             // per-wave Ps region

  // stage this wave's 32 Q rows into its Ps region (rot2 scheme)
  const int qr0 = qtile * 128 + wl * 32;
#pragma unroll
  for (int u = 0; u < 4; ++u) {
    int rotQ = (c8 + 8 * ((u * 4 + (r8 >> 1)) & 7)) & 63;
    glld16(qbase + (size_t)(qr0 + u * 8 + r8) * 2048 + rotQ, &Ps[pB + u * 8 * 64]);
  }
  // K/V tile 0 (cooperative: wave wv stages rows wv*8..+7)
  glld16(kbase + (size_t)(wv * 8 + r8) * 2048 + rotKV, &Ks[0][wv * 8 * 64]);
  glld16(vbase + (size_t)(wv * 8 + r8) * 2048 + rotKV, &Vts[0][wv * 8 * 64]);
  __syncthreads();
  short8 aq[2][2];
#pragma unroll
  for (int i = 0; i < 2; ++i) {
    aq[i][0] = *(const short8*)&Ps[pB + (i * 16 + l15) * 64 + pcol0];
    aq[i][1] = *(const short8*)&Ps[pB + (i * 16 + l15) * 64 + pcol1];
  }
  // NOTE: Ps region is wave-private (reads+writes only own region) — no
  // extra barrier needed before reusing it for P.

  short8 ones;
#pragma unroll
  for (int e = 0; e < 8; e++) ones[e] = (short)0x3F80;  // bf16 1.0

  float4v acc[2][4];
  float4v lacc[2];
#pragma unroll
  for (int i = 0; i < 2; ++i) {
    lacc[i] = zero4();
#pragma unroll
    for (int jt = 0; jt < 4; jt++) acc[i][jt] = zero4();
  }

  for (int kb = 0; kb <= lastH; ++kb) {
    const int cur = kb & 1;
    if (kb < lastH) {
      const int nb = cur ^ 1;
      glld16(kbase + (size_t)((kb + 1) * 64 + wv * 8 + r8) * 2048 + rotKV,
             &Ks[nb][wv * 8 * 64]);
      glld16(vbase + (size_t)(wv * 8 + r8) * 2048 + (kb + 1) * 64 + rotKV,
             &Vts[nb][wv * 8 * 64]);
    }
    if (wv < 4 || kb <= lastL) {
      // S = Q K^T
      float4v s[2][4];
#pragma unroll
      for (int i = 0; i < 2; ++i)
#pragma unroll
        for (int j = 0; j < 4; ++j) s[i][j] = zero4();
#pragma unroll
      for (int j = 0; j < 4; ++j) {
        short8 bk0 = *(const short8*)&Ks[cur][(j * 16 + l15) * 64 + colk0];
        short8 bk1 = *(const short8*)&Ks[cur][(j * 16 + l15) * 64 + colk1];
#pragma unroll
        for (int i = 0; i < 2; ++i) {
          s[i][j] = __builtin_amdgcn_mfma_f32_16x16x32_bf16(aq[i][0], bk0, s[i][j], 0, 0, 0);
          s[i][j] = __builtin_amdgcn_mfma_f32_16x16x32_bf16(aq[i][1], bk1, s[i][j], 0, 0, 0);
        }
      }
      // causal mask (only near-diagonal tiles)
#pragma unroll
      for (int i = 0; i < 2; ++i) {
        const int qrow_i = qtile * 128 + wl * 32 + i * 16;
        if (kb * 64 + 63 > qrow_i) {
#pragma unroll
          for (int j = 0; j < 4; ++j) {
            int key = kb * 64 + j * 16 + l15;
#pragma unroll
            for (int r = 0; r < 4; ++r)
              if (key > qrow_i + quad * 4 + r) s[i][j][r] = -1e30f;
          }
        }
      }
      // P = exp2(s) -> truncated bf16 into wave-private Ps (rot2 layout)
#pragma unroll
      for (int i = 0; i < 2; ++i)
#pragma unroll
        for (int j = 0; j < 4; ++j)
#pragma unroll
          for (int r = 0; r < 4; ++r) {
            float pv = exp2f(s[i][j][r]);
            union { float f; uint u; } cv; cv.f = pv;
            int wcol = (j * 16 + l15 + 64 - 8 * ((quad * 2 + (r >> 1)) & 7)) & 63;
            Ps[pB + (i * 16 + quad * 4 + r) * 64 + wcol] = (ushort)(cv.u >> 16);
          }
      // O += P V ; l += P 1
#pragma unroll
      for (int kt2 = 0; kt2 < 2; ++kt2) {
        const int vcol = kt2 ? colk1 : colk0;
        const int pcol = kt2 ? pcol1 : pcol0;
        short8 pa[2];
#pragma unroll
        for (int i = 0; i < 2; ++i) {
          pa[i] = *(const short8*)&Ps[pB + (i * 16 + l15) * 64 + pcol];
          lacc[i] = __builtin_amdgcn_mfma_f32_16x16x32_bf16(pa[i], ones, lacc[i], 0, 0, 0);
        }
#pragma unroll
        for (int jt = 0; jt < 4; ++jt) {
          short8 vb = *(const short8*)&Vts[cur][(jt * 16 + l15) * 64 + vcol];
#pragma unroll
          for (int i = 0; i < 2; ++i)
            acc[i][jt] = __builtin_amdgcn_mfma_f32_16x16x32_bf16(pa[i], vb, acc[i][jt], 0, 0, 0);
        }
      }
    }
    __syncthreads();  // drains prefetch glld + protects K/V buffer reuse
  }
#pragma unroll
  for (int i = 0; i < 2; ++i)
#pragma unroll
    for (int r = 0; r < 4; ++r) {
      float inv = __builtin_amdgcn_rcpf(lacc[i][r]);
      int t = qtile * 128 + wl * 32 + i * 16 + quad * 4 + r;
#pragma unroll
      for (int jt = 0; jt < 4; ++jt)
        y[(size_t)(b * 2048 + t) * 1024 + h * 64 + jt * 16 + l15] =
            f2b(acc[i][jt][r] * inv);
    }
}

extern "C" void kernel_launch(void* const* d_in, const int* in_sizes, int n_in,
                              void* d_out, int out_size, void* d_ws, size_t ws_size,
                              hipStream_t stream) {
  const float* x       = (const float*)d_in[0];
  const float* w_attn  = (const float*)d_in[1];
  const float* b_attn  = (const float*)d_in[2];
  const float* la_attn = (const float*)d_in[3];
  const float* lb_attn = (const float*)d_in[4];
  const float* w_proj  = (const float*)d_in[5];
  const float* b_proj  = (const float*)d_in[6];
  const float* la_proj = (const float*)d_in[7];
  const float* lb_proj = (const float*)d_in[8];

  ushort* p = (ushort*)d_ws;
  ushort* xb   = p; p += (size_t)4096 * 1024;
  ushort* wab  = p; p += (size_t)3072 * 1024;
  ushort* lab  = p; p += (size_t)32 * 1024;
  ushort* lbb  = p; p += (size_t)3072 * 32;
  ushort* wpb  = p; p += (size_t)1024 * 1024;
  ushort* lpb  = p; p += (size_t)32 * 1024;
  ushort* lqb  = p; p += (size_t)1024 * 32;
  ushort* t1b  = p; p += (size_t)4096 * 32;
  ushort* t2b  = p; p += (size_t)4096 * 32;
  ushort* qkb  = p; p += (size_t)4096 * 2048;   // Q|K halves (q pre-scaled)
  ushort* vtb  = p; p += (size_t)2048 * 2048;   // V transposed [b*1024+h*64+d][t]
  ushort* yb   = p; p += (size_t)4096 * 1024;

  convert_all<<<dim3(2048), dim3(256), 0, stream>>>(
      x, w_attn, la_attn, lb_attn, w_proj, la_proj, lb_proj,
      xb, wab, lab, lbb, wpb, lpb, lqb);
  lora_t<<<dim3(512), dim3(256), 0, stream>>>(xb, lab, t1b);
  gemm_lora<false, true, 24><<<dim3(768), dim3(256), 0, stream>>>(
      xb, wab, b_attn, t1b, lbb, qkb, vtb, 1024, 2048);
  flash_attn<<<dim3(256), dim3(512), 0, stream>>>(qkb, vtb, yb);
  lora_t<<<dim3(512), dim3(256), 0, stream>>>(yb, lpb, t2b);
  gemm_lora<true, false, 8><<<dim3(256), dim3(256), 0, stream>>>(
      yb, wpb, b_proj, t2b, lqb, d_out, nullptr, 1024, 1024);
}